// Round 1
// baseline (80.459 us; speedup 1.0000x reference)
//
#include <hip/hip_runtime.h>
#include <math.h>

// EquivEncoder fused: B=16, N_CTX=1024, 64x64 grid, fp32.
// out[b,c,iy,ix]: c0 = dens = sum_n w, c1 = (sum_n w*y0)/dens, c2 = (sum_n w*y1)/dens
// w = exp2(s*dx^2)*exp2(s*dy^2), s = -0.5*log2(e)*exp(-2*logl)
//
// R4 design: single kernel, ZERO workspace use (the 256 MiB ws poison fill was
// ~43 us of the 72.6 us budget; the split-kernel ws round-trip + 2nd launch the rest).
//  - 256 blocks = (16 b) x (16 grid tiles of 16x16); 1 block/CU, 256 threads, 1 cell/thread
//  - full n-loop per block, ping-pong LDS staging (NSTAGE=128) of separable
//    wx[i][n]=exp2(s*dx^2), wy[i][n]=exp2(s*dy^2) tables, TRANSPOSED so the
//    inner loop reads contiguous float4 along n  -> ds_read_b128
//  - row pad +4 floats: 132%32=4 -> 16 i-rows land on 8 banks, 2-way = free
//  - per Gram entry: 1 mul (w=wx*wy) + 1 add (dens) + 2 fma (s1,s2) = 4 VALU
//    -> 1024*4 = 4096 main VALU/thread ~= 3.5 us floor; tables ~15% on top

#define NB     16
#define NCTX   1024
#define NG     4096
#define NSTAGE 128
#define NCHUNK (NCTX / NSTAGE)
#define ROWLEN (NSTAGE + 4)

__global__ __launch_bounds__(256, 1)
void ee_fused(const float* __restrict__ X,
              const float* __restrict__ Y,
              const float* __restrict__ log_l_scale,
              float* __restrict__ out) {
    const int b    = blockIdx.x >> 4;
    const int tile = blockIdx.x & 15;
    const int ix0  = (tile & 3) * 16;    // tile x-origin in grid
    const int iy0  = (tile >> 2) * 16;   // tile y-origin in grid

    const float step  = 20.0f / 63.0f;
    const float scale = -0.72134752044448170f * expf(-2.0f * log_l_scale[0]);

    // transposed tables: [i][n], padded rows (132 floats = 528 B, 16B-aligned rows)
    __shared__ float wxs[2][16][ROWLEN];   // 2 x 16.9 KB
    __shared__ float wys[2][16][ROWLEN];   // 2 x 16.9 KB
    __shared__ float y0s[2][NSTAGE];       // 1 KB
    __shared__ float y1s[2][NSTAGE];       // 1 KB   total ~37 KB

    const float2* Xb = (const float2*)(X + (size_t)b * NCTX * 2);
    const float2* Yb = (const float2*)(Y + (size_t)b * NCTX * 2);

    const int t   = threadIdx.x;
    const int ixl = t & 15;       // this thread's cell within the tile
    const int iyl = t >> 4;

    // stage chunk c into buffer p: 16x128 wx + 16x128 wy entries, 256 threads
    // thread handles n = t&127, i = 2e + (t>>7)  (e = 0..7) -> 16 exp2/thread
    auto build = [&](int c, int p) {
        const int n0 = c * NSTAGE;
        const int n  = t & (NSTAGE - 1);
        const int ih = t >> 7;                  // 0 or 1
        const float2 xv = Xb[n0 + n];           // one 8B load, L1-resident after c=0
        const float bx = -10.0f + step * (float)ix0 - xv.x;
        const float by =  10.0f - step * (float)iy0 - xv.y;
#pragma unroll
        for (int e = 0; e < 8; ++e) {
            const int i = 2 * e + ih;
            const float dx = bx + step * (float)i;
            const float dy = by - step * (float)i;
            wxs[p][i][n] = exp2f(dx * dx * scale);
            wys[p][i][n] = exp2f(dy * dy * scale);
        }
        if (t < NSTAGE) {
            const float2 yv = Yb[n0 + t];
            y0s[p][t] = yv.x;
            y1s[p][t] = yv.y;
        }
    };

    float dens = 0.0f, s1 = 0.0f, s2 = 0.0f;

    build(0, 0);
    __syncthreads();

    for (int c = 0; c < NCHUNK; ++c) {
        const int p = c & 1;
        // prefetch next chunk into the other buffer (its last readers synced already)
        if (c + 1 < NCHUNK) build(c + 1, p ^ 1);

#pragma unroll 4
        for (int n4 = 0; n4 < NSTAGE; n4 += 4) {
            const float4 wx4 = *(const float4*)&wxs[p][ixl][n4];  // b128, 2-way = free
            const float4 wy4 = *(const float4*)&wys[p][iyl][n4];  // b128, 4-addr broadcast
            const float4 ya  = *(const float4*)&y0s[p][n4];       // uniform broadcast
            const float4 yb  = *(const float4*)&y1s[p][n4];
            float w;
            w = wx4.x * wy4.x; dens += w; s1 = fmaf(w, ya.x, s1); s2 = fmaf(w, yb.x, s2);
            w = wx4.y * wy4.y; dens += w; s1 = fmaf(w, ya.y, s1); s2 = fmaf(w, yb.y, s2);
            w = wx4.z * wy4.z; dens += w; s1 = fmaf(w, ya.z, s1); s2 = fmaf(w, yb.z, s2);
            w = wx4.w * wy4.w; dens += w; s1 = fmaf(w, ya.w, s1); s2 = fmaf(w, yb.w, s2);
        }
        __syncthreads();   // one barrier/chunk: protects both ping-pong buffers
    }

    // epilogue: out[b][c][g], g = iy*64 + ix
    const int g = (iy0 + iyl) * 64 + (ix0 + ixl);
    float* ob = out + (size_t)b * 3 * NG;
    const float inv = 1.0f / dens;    // dens > 0 (sum of exps)
    ob[g]          = dens;
    ob[NG + g]     = s1 * inv;
    ob[2 * NG + g] = s2 * inv;
}

extern "C" void kernel_launch(void* const* d_in, const int* in_sizes, int n_in,
                              void* d_out, int out_size, void* d_ws, size_t ws_size,
                              hipStream_t stream) {
    const float* X    = (const float*)d_in[0];   // (16,1024,2) fp32
    const float* Y    = (const float*)d_in[1];   // (16,1024,2) fp32
    const float* logl = (const float*)d_in[2];   // scalar fp32
    float* out = (float*)d_out;                  // (16,3,64,64) fp32
    (void)d_ws; (void)ws_size;                   // workspace intentionally unused

    ee_fused<<<dim3(NB * 16), dim3(256), 0, stream>>>(X, Y, logl, out);
}

// Round 2
// 73.289 us; speedup vs baseline: 1.0978x; 1.0978x over previous
//
#include <hip/hip_runtime.h>
#include <math.h>

// EquivEncoder: B=16, N_CTX=1024, 64x64 grid, fp32.
// out[b,c,iy,ix]: c0 = dens = sum_n w, c1 = (sum_n w*y0)/dens, c2 = (sum_n w*y1)/dens
// w = exp2(s*dx^2)*exp2(s*dy^2), s = -0.5*log2(e)*exp(-2*logl)
//
// R5 = R3 structure (4x4 register tile, 2.5 B LDS/entry -- R4's 1-cell/thread
// fused variant regressed to 16 B/entry, LDS-issue bound) + XCD-aware block
// mapping. The 256 MiB ws poison fill (~40 us @6.7 TB/s) is unconditional
// harness reset() work on the timed stream: floor = 40 us + our kernels.
//
// XCD remap: blockIdx % 8 = XCD (round-robin, m09). With bid = nc*16 + b
// (partial) and bid = j*16 + b (reduce), all 16 n-splits AND all 16 reducer
// blocks of batch b sit on XCD b%8. The 790 KB partial slice per b stays
// dirty in that XCD's 4 MiB L2 (2 b/XCD = 1.6 MB), so the reduce reads are
// local L2 hits instead of cross-XCD coherence traffic (~6-12 us in R0/R3).

#define NB     16
#define NCTX   1024
#define NG     4096
#define NSPLIT 16
#define NC     64      // NCTX / NSPLIT

__global__ __launch_bounds__(256, 1)
void ee_partial(const float* __restrict__ X,
                const float* __restrict__ Y,
                const float* __restrict__ log_l_scale,
                float* __restrict__ ws) {
    // bid = nc*16 + b  ->  XCD = b % 8 for all splits of b
    const int b  = blockIdx.x & 15;
    const int nc = blockIdx.x >> 4;
    const int n0 = nc * NC;

    const float step  = 20.0f / 63.0f;
    const float scale = -0.72134752044448170f * expf(-2.0f * log_l_scale[0]);

    __shared__ float  wx[NC][64];    // 16 KB  exp2(s*dx^2) for (n, ix)
    __shared__ float  wy[NC][64];    // 16 KB  exp2(s*dy^2) for (n, iy)
    __shared__ float2 sy[NC];        // 512 B  (y0, y1)

    const float2* Xb = (const float2*)(X + (size_t)b * NCTX * 2);
    const float2* Yb = (const float2*)(Y + (size_t)b * NCTX * 2);

    // --- tables: 16 iters/thread, one 8B global load + 2 exps each ---
    for (int idx = threadIdx.x; idx < NC * 64; idx += 256) {
        const int j = idx >> 6, i = idx & 63;
        const float2 xv = Xb[n0 + j];
        const float dx = (-10.0f + step * (float)i) - xv.x;
        const float dy = ( 10.0f - step * (float)i) - xv.y;
        wx[j][i] = exp2f(dx * dx * scale);
        wy[j][i] = exp2f(dy * dy * scale);
    }
    if (threadIdx.x < NC) sy[threadIdx.x] = Yb[n0 + threadIdx.x];
    __syncthreads();

    // --- 4x4 cell tile per thread: ix0 = 4*tx, iy = 4*ty + s ---
    const int tx = threadIdx.x & 15;
    const int ty = threadIdx.x >> 4;
    const int ix0 = tx * 4;
    const int iy0 = ty * 4;

    float4 ad[4] = {{0,0,0,0},{0,0,0,0},{0,0,0,0},{0,0,0,0}};  // dens
    float4 a1[4] = {{0,0,0,0},{0,0,0,0},{0,0,0,0},{0,0,0,0}};  // sum w*y0
    float4 a2[4] = {{0,0,0,0},{0,0,0,0},{0,0,0,0},{0,0,0,0}};  // sum w*y1

#pragma unroll 4
    for (int n = 0; n < NC; ++n) {
        const float4 wxv = *(const float4*)&wx[n][ix0];  // contiguous row b128
        const float4 wyv = *(const float4*)&wy[n][iy0];  // 4-addr broadcast b128
        const float2 yv  = sy[n];                        // full broadcast
        const float wys[4] = {wyv.x, wyv.y, wyv.z, wyv.w};
#pragma unroll
        for (int s = 0; s < 4; ++s) {
            const float w  = wys[s];
            const float q1 = w * yv.x;
            const float q2 = w * yv.y;
            ad[s].x = fmaf(wxv.x, w, ad[s].x);  ad[s].y = fmaf(wxv.y, w, ad[s].y);
            ad[s].z = fmaf(wxv.z, w, ad[s].z);  ad[s].w = fmaf(wxv.w, w, ad[s].w);
            a1[s].x = fmaf(wxv.x, q1, a1[s].x); a1[s].y = fmaf(wxv.y, q1, a1[s].y);
            a1[s].z = fmaf(wxv.z, q1, a1[s].z); a1[s].w = fmaf(wxv.w, q1, a1[s].w);
            a2[s].x = fmaf(wxv.x, q2, a2[s].x); a2[s].y = fmaf(wxv.y, q2, a2[s].y);
            a2[s].z = fmaf(wxv.z, q2, a2[s].z); a2[s].w = fmaf(wxv.w, q2, a2[s].w);
        }
    }

    // --- partials: ws[b][nc][c][g], float4 stores (stay dirty in local L2) ---
    float* base = ws + ((size_t)(b * NSPLIT + nc)) * 3 * NG;
#pragma unroll
    for (int s = 0; s < 4; ++s) {
        const int g = (iy0 + s) * 64 + ix0;
        *(float4*)&base[g]          = ad[s];
        *(float4*)&base[NG + g]     = a1[s];
        *(float4*)&base[2*NG + g]   = a2[s];
    }
}

__global__ __launch_bounds__(256)
void ee_reduce(const float* __restrict__ ws, float* __restrict__ out) {
    // bid = j*16 + b  ->  same XCD (b % 8) as the partial writers of batch b
    const int b = blockIdx.x & 15;
    const int j = blockIdx.x >> 4;
    const int g = j * 256 + (int)threadIdx.x;       // 16 blocks x 256 = 4096 cells
    const float* base = ws + (size_t)b * NSPLIT * 3 * NG;
    float a0 = 0, a1 = 0, a2 = 0;
#pragma unroll
    for (int nc = 0; nc < NSPLIT; ++nc) {
        const float* p = base + nc * 3 * NG;
        a0 += p[g];
        a1 += p[NG + g];
        a2 += p[2 * NG + g];
    }
    const float inv = 1.0f / a0;   // a0 > 0 (sum of exps)
    float* ob = out + (size_t)b * 3 * NG;
    ob[g]          = a0;
    ob[NG + g]     = a1 * inv;
    ob[2 * NG + g] = a2 * inv;
}

extern "C" void kernel_launch(void* const* d_in, const int* in_sizes, int n_in,
                              void* d_out, int out_size, void* d_ws, size_t ws_size,
                              hipStream_t stream) {
    const float* X    = (const float*)d_in[0];   // (16,1024,2) fp32
    const float* Y    = (const float*)d_in[1];   // (16,1024,2) fp32
    const float* logl = (const float*)d_in[2];   // scalar fp32
    float* out = (float*)d_out;                  // (16,3,64,64) fp32
    float* ws  = (float*)d_ws;                   // 16*16*3*4096*4 = 12.6 MB

    ee_partial<<<dim3(NB * NSPLIT), dim3(256), 0, stream>>>(X, Y, logl, ws);
    ee_reduce <<<dim3(NB * NSPLIT), dim3(256), 0, stream>>>(ws, out);
}